// Round 1
// baseline (2101.192 us; speedup 1.0000x reference)
//
#include <hip/hip_runtime.h>
#include <hip/hip_bf16.h>
#include <math.h>

// Problem constants (match reference)
#define BB 2
#define SS 2048
#define DD 1024
#define HH 16
#define DEPTH 64
#define MTOT (BB*SS)   // 4096 rows

__device__ __forceinline__ float silu_f(float x) {
    return x / (1.0f + __expf(-x));
}

// ---------------------------------------------------------------------------
// C[M,N] = silu(A[M,K] @ W[K,N] + bias[N])
// 64x64 tile, BK=16, 256 threads, 4x4 microtile per thread.
// ---------------------------------------------------------------------------
__global__ __launch_bounds__(256) void gemm_bias_silu(
    const float* __restrict__ A, const float* __restrict__ W,
    const float* __restrict__ bias, float* __restrict__ C,
    int M, int N, int Kd)
{
    __shared__ float Ast[16][68];   // transposed A tile: Ast[k][row]
    __shared__ float Ws[16][68];    // Ws[k][col]
    const int t   = threadIdx.x;
    const int brow = blockIdx.y << 6;
    const int bcol = blockIdx.x << 6;
    const int tx = t & 15;          // col group
    const int ty = t >> 4;          // row group
    // A loader: thread t loads float4 at (row = t>>2, k = (t&3)*4)
    const int lrowA = t >> 2;
    const int lkA   = (t & 3) << 2;
    // W loader: thread t loads float4 at (k = t>>4, col = (t&15)*4)
    const int lkW   = t >> 4;
    const int lcolW = (t & 15) << 2;

    const float* Aload = A + (size_t)(brow + lrowA) * Kd + lkA;
    const float* Wload = W + (size_t)lkW * N + bcol + lcolW;

    float acc[4][4];
    #pragma unroll
    for (int i = 0; i < 4; ++i)
        #pragma unroll
        for (int j = 0; j < 4; ++j) acc[i][j] = 0.0f;

    for (int k0 = 0; k0 < Kd; k0 += 16) {
        const float4 a4 = *(const float4*)(Aload + k0);
        const float4 w4 = *(const float4*)(Wload + (size_t)k0 * N);
        // store A transposed (scalar stores; 2-way bank alias at worst = free)
        Ast[lkA + 0][lrowA] = a4.x;
        Ast[lkA + 1][lrowA] = a4.y;
        Ast[lkA + 2][lrowA] = a4.z;
        Ast[lkA + 3][lrowA] = a4.w;
        Ws[lkW][lcolW + 0] = w4.x;
        Ws[lkW][lcolW + 1] = w4.y;
        Ws[lkW][lcolW + 2] = w4.z;
        Ws[lkW][lcolW + 3] = w4.w;
        __syncthreads();
        #pragma unroll
        for (int kk = 0; kk < 16; ++kk) {
            const float4 av = *(const float4*)(&Ast[kk][ty << 2]);
            const float4 bv = *(const float4*)(&Ws[kk][tx << 2]);
            const float a[4] = {av.x, av.y, av.z, av.w};
            const float b[4] = {bv.x, bv.y, bv.z, bv.w};
            #pragma unroll
            for (int i = 0; i < 4; ++i)
                #pragma unroll
                for (int j = 0; j < 4; ++j)
                    acc[i][j] = fmaf(a[i], b[j], acc[i][j]);
        }
        __syncthreads();
    }

    // epilogue: bias + silu, vectorized store
    float bsv[4];
    #pragma unroll
    for (int j = 0; j < 4; ++j) bsv[j] = bias[bcol + (tx << 2) + j];
    #pragma unroll
    for (int i = 0; i < 4; ++i) {
        const int row = brow + (ty << 2) + i;
        float4 o;
        o.x = silu_f(acc[i][0] + bsv[0]);
        o.y = silu_f(acc[i][1] + bsv[1]);
        o.z = silu_f(acc[i][2] + bsv[2]);
        o.w = silu_f(acc[i][3] + bsv[3]);
        *(float4*)(C + (size_t)row * N + bcol + (tx << 2)) = o;
    }
}

// ---------------------------------------------------------------------------
// Depthwise conv, K=3, padding SAME, per-channel kernels dw[3][D].
// y[b,s,c] = x[b,s-1,c]*dw[0,c] + x[b,s,c]*dw[1,c] + x[b,s+1,c]*dw[2,c]
// ---------------------------------------------------------------------------
__global__ __launch_bounds__(256) void dwconv3(
    const float* __restrict__ x, const float* __restrict__ dw,
    float* __restrict__ y)
{
    const size_t idx = (size_t)blockIdx.x * blockDim.x + threadIdx.x;
    if (idx >= (size_t)BB * SS * DD) return;
    const int c = (int)(idx % DD);
    const size_t sb = idx / DD;
    const int s = (int)(sb % SS);
    float acc = x[idx] * dw[DD + c];
    if (s > 0)      acc = fmaf(x[idx - DD], dw[c], acc);
    if (s < SS - 1) acc = fmaf(x[idx + DD], dw[2 * DD + c], acc);
    y[idx] = acc;
}

// ---------------------------------------------------------------------------
// Attention: one thread per query row; two passes (max, then exp/accum).
// Q,Kc,V: [B,S,D] merged-head layout; head h occupies cols h*64..h*64+63.
// mask: [B,S] int (1 = masked out). O: [B,S,D] merged-head layout.
// grid: (S/256, H, B), block 256.
// ---------------------------------------------------------------------------
__global__ __launch_bounds__(256) void attn_fp32(
    const float* __restrict__ Q, const float* __restrict__ Kc,
    const float* __restrict__ V, const int* __restrict__ mask,
    float* __restrict__ O)
{
    __shared__ float Ks[64][64];
    __shared__ float Vs[64][64];
    __shared__ int   mk[64];

    const int b = blockIdx.z, h = blockIdx.y;
    const int t = threadIdx.x;
    const int row = (blockIdx.x << 8) + t;
    const size_t qbase = ((size_t)b * SS + row) * DD + h * DEPTH;
    const int maskbase = b * SS;

    float q[64];
    #pragma unroll
    for (int d4 = 0; d4 < 16; ++d4) {
        const float4 v4 = *(const float4*)(Q + qbase + d4 * 4);
        q[d4*4+0] = v4.x; q[d4*4+1] = v4.y; q[d4*4+2] = v4.z; q[d4*4+3] = v4.w;
    }

    // ---- pass 1: row max of scaled logits over unmasked keys ----
    float m = -1e30f;
    for (int kt = 0; kt < SS; kt += 64) {
        #pragma unroll
        for (int i = 0; i < 4; ++i) {
            const int f = t + i * 256;          // float4 id 0..1023
            const int r = f >> 4, c4 = (f & 15) << 2;
            *(float4*)(&Ks[r][c4]) =
                *(const float4*)(Kc + ((size_t)b * SS + kt + r) * DD + h * DEPTH + c4);
        }
        if (t < 64) mk[t] = mask[maskbase + kt + t];
        __syncthreads();
        for (int kk = 0; kk < 64; ++kk) {
            if (mk[kk]) continue;               // uniform branch per block
            float dot = 0.0f;
            #pragma unroll
            for (int d = 0; d < 64; ++d) dot = fmaf(q[d], Ks[kk][d], dot);
            m = fmaxf(m, dot * 0.125f);
        }
        __syncthreads();
    }

    // ---- pass 2: weights + weighted V accumulation ----
    float l = 0.0f;
    float acc[64];
    #pragma unroll
    for (int d = 0; d < 64; ++d) acc[d] = 0.0f;

    for (int kt = 0; kt < SS; kt += 64) {
        #pragma unroll
        for (int i = 0; i < 4; ++i) {
            const int f = t + i * 256;
            const int r = f >> 4, c4 = (f & 15) << 2;
            const size_t g = ((size_t)b * SS + kt + r) * DD + h * DEPTH + c4;
            *(float4*)(&Ks[r][c4]) = *(const float4*)(Kc + g);
            *(float4*)(&Vs[r][c4]) = *(const float4*)(V + g);
        }
        if (t < 64) mk[t] = mask[maskbase + kt + t];
        __syncthreads();
        for (int kk = 0; kk < 64; ++kk) {
            if (mk[kk]) continue;
            float dot = 0.0f;
            #pragma unroll
            for (int d = 0; d < 64; ++d) dot = fmaf(q[d], Ks[kk][d], dot);
            const float w = __expf(dot * 0.125f - m);
            l += w;
            #pragma unroll
            for (int d = 0; d < 64; ++d) acc[d] = fmaf(w, Vs[kk][d], acc[d]);
        }
        __syncthreads();
    }

    const float inv = 1.0f / l;
    #pragma unroll
    for (int d4 = 0; d4 < 16; ++d4) {
        float4 o;
        o.x = acc[d4*4+0] * inv;
        o.y = acc[d4*4+1] * inv;
        o.z = acc[d4*4+2] * inv;
        o.w = acc[d4*4+3] * inv;
        *(float4*)(O + qbase + d4 * 4) = o;
    }
}

// ---------------------------------------------------------------------------
extern "C" void kernel_launch(void* const* d_in, const int* in_sizes, int n_in,
                              void* d_out, int out_size, void* d_ws, size_t ws_size,
                              hipStream_t stream) {
    const float* v     = (const float*)d_in[0];
    const float* k     = (const float*)d_in[1];
    const float* q     = (const float*)d_in[2];
    const int*   mask  = (const int*)  d_in[3];
    const float* wq_w  = (const float*)d_in[4];
    const float* wq_b  = (const float*)d_in[5];
    const float* wk_w  = (const float*)d_in[6];
    const float* wk_b  = (const float*)d_in[7];
    const float* wv_w  = (const float*)d_in[8];
    const float* wv_b  = (const float*)d_in[9];
    const float* dwq   = (const float*)d_in[10];
    const float* pwq   = (const float*)d_in[11];
    const float* bq    = (const float*)d_in[12];
    const float* dwk   = (const float*)d_in[13];
    const float* pwk   = (const float*)d_in[14];
    const float* bk    = (const float*)d_in[15];
    const float* dwv   = (const float*)d_in[16];
    const float* pwv   = (const float*)d_in[17];
    const float* bv    = (const float*)d_in[18];
    const float* wo_w  = (const float*)d_in[19];
    const float* wo_b  = (const float*)d_in[20];
    float* out = (float*)d_out;

    const size_t NE = (size_t)BB * SS * DD;   // 4M floats = 16 MB
    float* s0 = (float*)d_ws;                 // qp -> qc
    float* s1 = s0 + NE;                      // kp -> kc
    float* s2 = s1 + NE;                      // vp -> vc
    float* s3 = s2 + NE;                      // depthwise temp
    float* s4 = s3 + NE;                      // attention out

    const dim3 gg(DD / 64, MTOT / 64);        // (16, 64)
    const int nblk = (int)(NE / 256);         // 16384

    // Dense projections + SiLU
    gemm_bias_silu<<<gg, 256, 0, stream>>>(q, wq_w, wq_b, s0, MTOT, DD, DD);
    gemm_bias_silu<<<gg, 256, 0, stream>>>(k, wk_w, wk_b, s1, MTOT, DD, DD);
    gemm_bias_silu<<<gg, 256, 0, stream>>>(v, wv_w, wv_b, s2, MTOT, DD, DD);

    // SeparableConv1D (depthwise -> pointwise GEMM + bias + SiLU)
    dwconv3<<<nblk, 256, 0, stream>>>(s0, dwq, s3);
    gemm_bias_silu<<<gg, 256, 0, stream>>>(s3, pwq, bq, s0, MTOT, DD, DD);
    dwconv3<<<nblk, 256, 0, stream>>>(s1, dwk, s3);
    gemm_bias_silu<<<gg, 256, 0, stream>>>(s3, pwk, bk, s1, MTOT, DD, DD);
    dwconv3<<<nblk, 256, 0, stream>>>(s2, dwv, s3);
    gemm_bias_silu<<<gg, 256, 0, stream>>>(s3, pwv, bv, s2, MTOT, DD, DD);

    // Attention
    const dim3 ga(SS / 256, HH, BB);          // (8, 16, 2)
    attn_fp32<<<ga, 256, 0, stream>>>(s0, s1, s2, mask, s4);

    // Output dense + SiLU
    gemm_bias_silu<<<gg, 256, 0, stream>>>(s4, wo_w, wo_b, out, MTOT, DD, DD);
}

// Round 2
// 409.430 us; speedup vs baseline: 5.1320x; 5.1320x over previous
//
#include <hip/hip_runtime.h>
#include <hip/hip_bf16.h>
#include <hip/hip_fp16.h>
#include <math.h>

#define BB 2
#define SS 2048
#define DD 1024
#define HH 16
#define DEPTH 64
#define MTOT (BB*SS)   // 4096

typedef _Float16 f16;
typedef _Float16 f16x4 __attribute__((ext_vector_type(4)));
typedef _Float16 f16x8 __attribute__((ext_vector_type(8)));
typedef float    f32x4 __attribute__((ext_vector_type(4)));

__device__ __forceinline__ float silu_f(float x) {
    return x / (1.0f + __expf(-x));
}

// ---------------------------------------------------------------------------
// C = silu(A[M,1024] @ W[1024,N] + bias). A,W fp32. OUTF16: write f16 else f32.
// 128x128 tile, BK=32, 256 threads (4 waves, 2x2), mfma_f32_16x16x32_f16.
// ---------------------------------------------------------------------------
template<int OUTF16>
__global__ __launch_bounds__(256) void gemm_f16mfma(
    const float* __restrict__ A, const float* __restrict__ W,
    const float* __restrict__ bias, float* __restrict__ Cf,
    f16* __restrict__ Ch, int N)
{
    __shared__ f16 As[128][40];   // row-major [m][k], 80B stride
    __shared__ f16 Bs[128][40];   // n-major  [n][k], 80B stride

    const int t  = threadIdx.x;
    const int l  = t & 63;
    const int wv = t >> 6;
    const int lr = l & 15, lg = l >> 4;
    const int wr = wv >> 1, wc = wv & 1;

    // bijective XCD swizzle: consecutive row-panels per XCD (A-panel L2 reuse)
    const int nwg = gridDim.x * gridDim.y;
    const int bid = blockIdx.y * gridDim.x + blockIdx.x;
    const int per = nwg >> 3;
    const int sw  = (bid & 7) * per + (bid >> 3);
    const int bx  = sw % gridDim.x, by = sw / gridDim.x;
    const int brow = by << 7, bcol = bx << 7;

    // A stage mapping: fid = t + 256*i -> (r = fid>>3, c = (fid&7)*4)
    // B stage mapping: 4x4 transpose block, bk4 = (t&7)*4 k-rows, bn4 = (t>>3)*4 cols
    const int bk4 = (t & 7) << 2;
    const int bn4 = (t >> 3) << 2;

    float areg[4][4], wreg[4][4];

#define LOADT(KT) do {                                                        \
    const int k0 = (KT) << 5;                                                 \
    _Pragma("unroll")                                                         \
    for (int i = 0; i < 4; ++i) {                                             \
        const int fid = t + (i << 8);                                         \
        const int r = fid >> 3, c = (fid & 7) << 2;                           \
        const float4 v4 = *(const float4*)(A + (size_t)(brow + r) * 1024 + k0 + c); \
        areg[i][0] = v4.x; areg[i][1] = v4.y; areg[i][2] = v4.z; areg[i][3] = v4.w; \
    }                                                                         \
    _Pragma("unroll")                                                         \
    for (int r = 0; r < 4; ++r) {                                             \
        const float4 v4 = *(const float4*)(W + (size_t)(k0 + bk4 + r) * N + bcol + bn4); \
        wreg[r][0] = v4.x; wreg[r][1] = v4.y; wreg[r][2] = v4.z; wreg[r][3] = v4.w; \
    }                                                                         \
} while (0)

#define WRITET() do {                                                         \
    _Pragma("unroll")                                                         \
    for (int i = 0; i < 4; ++i) {                                             \
        const int fid = t + (i << 8);                                         \
        const int r = fid >> 3, c = (fid & 7) << 2;                           \
        f16x4 h4 = { (f16)areg[i][0], (f16)areg[i][1], (f16)areg[i][2], (f16)areg[i][3] }; \
        *(f16x4*)&As[r][c] = h4;                                              \
    }                                                                         \
    _Pragma("unroll")                                                         \
    for (int j = 0; j < 4; ++j) {                                             \
        f16x4 h4 = { (f16)wreg[0][j], (f16)wreg[1][j], (f16)wreg[2][j], (f16)wreg[3][j] }; \
        *(f16x4*)&Bs[bn4 + j][bk4] = h4;                                      \
    }                                                                         \
} while (0)

    f32x4 acc[4][4];
    #pragma unroll
    for (int m = 0; m < 4; ++m)
        #pragma unroll
        for (int n = 0; n < 4; ++n)
            acc[m][n] = (f32x4){0.f, 0.f, 0.f, 0.f};

    LOADT(0);
    WRITET();
    __syncthreads();

    for (int kt = 0; kt < 32; ++kt) {
        if (kt + 1 < 32) LOADT(kt + 1);   // issue-early prefetch (hides HBM under MFMA)

        f16x8 af[4], bf[4];
        #pragma unroll
        for (int m = 0; m < 4; ++m)
            af[m] = *(const f16x8*)&As[(wr << 6) + (m << 4) + lr][lg << 3];
        #pragma unroll
        for (int n = 0; n < 4; ++n)
            bf[n] = *(const f16x8*)&Bs[(wc << 6) + (n << 4) + lr][lg << 3];
        #pragma unroll
        for (int m = 0; m < 4; ++m)
            #pragma unroll
            for (int n = 0; n < 4; ++n)
                acc[m][n] = __builtin_amdgcn_mfma_f32_16x16x32_f16(af[m], bf[n], acc[m][n], 0, 0, 0);

        if (kt + 1 < 32) {
            __syncthreads();
            WRITET();
            __syncthreads();
        }
    }
#undef LOADT
#undef WRITET

    // epilogue: bias + silu
    float bv[4];
    #pragma unroll
    for (int n = 0; n < 4; ++n)
        bv[n] = bias[bcol + (wc << 6) + (n << 4) + lr];
    #pragma unroll
    for (int m = 0; m < 4; ++m)
        #pragma unroll
        for (int n = 0; n < 4; ++n)
            #pragma unroll
            for (int i = 0; i < 4; ++i) {
                const int row = brow + (wr << 6) + (m << 4) + (lg << 2) + i;
                const int col = bcol + (wc << 6) + (n << 4) + lr;
                const float o = silu_f(acc[m][n][i] + bv[n]);
                if (OUTF16) Ch[(size_t)row * N + col] = (f16)o;
                else        Cf[(size_t)row * N + col] = o;
            }
}

// ---------------------------------------------------------------------------
// Depthwise conv K=3, SAME. fp32 in/out.
// ---------------------------------------------------------------------------
__global__ __launch_bounds__(256) void dwconv3(
    const float* __restrict__ x, const float* __restrict__ dw,
    float* __restrict__ y)
{
    const size_t idx = (size_t)blockIdx.x * blockDim.x + threadIdx.x;
    const int c = (int)(idx % DD);
    const size_t sb = idx / DD;
    const int s = (int)(sb % SS);
    float acc = x[idx] * dw[DD + c];
    if (s > 0)      acc = fmaf(x[idx - DD], dw[c], acc);
    if (s < SS - 1) acc = fmaf(x[idx + DD], dw[2 * DD + c], acc);
    y[idx] = acc;
}

// ---------------------------------------------------------------------------
// Flash attention, f16 MFMA, fp32 softmax/accum.
// Q,K,V f16 [B*S][1024] head-merged; O fp32 same layout. 64 q-rows per block,
// 4 waves x 16 rows; 64-key tiles. grid 1024 blocks (XCD-swizzled), 256 thr.
// ---------------------------------------------------------------------------
__global__ __launch_bounds__(256) void attn_f16(
    const f16* __restrict__ Q, const f16* __restrict__ K,
    const f16* __restrict__ V, const int* __restrict__ mask,
    float* __restrict__ O)
{
    __shared__ f16 Ks[64][72];      // [key][d], 144B stride
    __shared__ f16 Vt[64][72];      // [d][key] transposed
    __shared__ f16 Pw[4][16][72];   // per-wave P scratch [qrow][key]
    __shared__ int mk[64];

    const int t = threadIdx.x;
    const int l = t & 63, wv = t >> 6;
    const int lr = l & 15, lg = l >> 4;

    // swizzle: each XCD owns contiguous sw-range -> same (b,h) K/V reuse in L2
    const int bid = blockIdx.x;                 // 0..1023
    const int sw  = (bid & 7) * 128 + (bid >> 3);
    const int qb  = (sw & 31) << 6;
    const int h   = (sw >> 5) & 15;
    const int b   = sw >> 9;

    // V-transpose staging block
    const int bkv = (t & 15) << 2;   // key 0..60
    const int bnv = (t >> 4) << 2;   // d   0..60

    // Q fragments direct from global (hoisted)
    const size_t qrow = (size_t)b * SS + qb + (wv << 4) + lr;
    f16x8 aq0 = *(const f16x8*)(Q + qrow * DD + h * DEPTH + (lg << 3));
    f16x8 aq1 = *(const f16x8*)(Q + qrow * DD + h * DEPTH + 32 + (lg << 3));

    float m_i[4], l_i[4];
    f32x4 acc[4];
    #pragma unroll
    for (int i = 0; i < 4; ++i) { m_i[i] = -1e30f; l_i[i] = 0.f; }
    #pragma unroll
    for (int n = 0; n < 4; ++n) acc[n] = (f32x4){0.f, 0.f, 0.f, 0.f};

    for (int kt = 0; kt < SS; kt += 64) {
        // ---- stage K (natural) ----
        #pragma unroll
        for (int i = 0; i < 4; ++i) {
            const int fid = t + (i << 8);
            const int r = fid >> 4, c = (fid & 15) << 2;
            *(f16x4*)&Ks[r][c] =
                *(const f16x4*)(K + ((size_t)b * SS + kt + r) * DD + h * DEPTH + c);
        }
        // ---- stage V transposed ----
        {
            f16x4 vl[4];
            #pragma unroll
            for (int r = 0; r < 4; ++r)
                vl[r] = *(const f16x4*)(V + ((size_t)b * SS + kt + bkv + r) * DD + h * DEPTH + bnv);
            #pragma unroll
            for (int j = 0; j < 4; ++j) {
                f16x4 h4 = { vl[0][j], vl[1][j], vl[2][j], vl[3][j] };
                *(f16x4*)&Vt[bnv + j][bkv] = h4;
            }
        }
        if (t < 64) mk[t] = mask[b * SS + kt + t];
        __syncthreads();

        // ---- S = Q K^T (per wave: 16 rows x 64 keys) ----
        f32x4 s[4];
        #pragma unroll
        for (int n = 0; n < 4; ++n) {
            const f16x8 bk0 = *(const f16x8*)&Ks[(n << 4) + lr][lg << 3];
            const f16x8 bk1 = *(const f16x8*)&Ks[(n << 4) + lr][32 + (lg << 3)];
            f32x4 z = (f32x4){0.f, 0.f, 0.f, 0.f};
            z = __builtin_amdgcn_mfma_f32_16x16x32_f16(aq0, bk0, z, 0, 0, 0);
            z = __builtin_amdgcn_mfma_f32_16x16x32_f16(aq1, bk1, z, 0, 0, 0);
            const int msk = mk[(n << 4) + lr];
            #pragma unroll
            for (int i = 0; i < 4; ++i)
                s[n][i] = msk ? -1e30f : z[i] * 0.125f;
        }

        // ---- online softmax (row = lg*4 + i, owned by 16-lane group) ----
        float pm[4];
        #pragma unroll
        for (int i = 0; i < 4; ++i)
            pm[i] = fmaxf(fmaxf(s[0][i], s[1][i]), fmaxf(s[2][i], s[3][i]));
        #pragma unroll
        for (int i = 0; i < 4; ++i) {
            pm[i] = fmaxf(pm[i], __shfl_xor(pm[i], 1));
            pm[i] = fmaxf(pm[i], __shfl_xor(pm[i], 2));
            pm[i] = fmaxf(pm[i], __shfl_xor(pm[i], 4));
            pm[i] = fmaxf(pm[i], __shfl_xor(pm[i], 8));
        }
        float sc[4];
        #pragma unroll
        for (int i = 0; i < 4; ++i) {
            const float mn = fmaxf(m_i[i], pm[i]);
            sc[i] = __expf(m_i[i] - mn);
            m_i[i] = mn;
            l_i[i] *= sc[i];
        }
        #pragma unroll
        for (int n = 0; n < 4; ++n)
            #pragma unroll
            for (int i = 0; i < 4; ++i)
                acc[n][i] *= sc[i];

        // P = exp(s - m), accumulate lane-partial row sums, write to Pw
        #pragma unroll
        for (int n = 0; n < 4; ++n)
            #pragma unroll
            for (int i = 0; i < 4; ++i) {
                const float p = __expf(s[n][i] - m_i[i]);
                l_i[i] += p;
                Pw[wv][(lg << 2) + i][(n << 4) + lr] = (f16)p;
            }

        // ---- O += P V (A-frags from Pw, B-frags from Vt) ----
        const f16x8 pa0 = *(const f16x8*)&Pw[wv][lr][lg << 3];
        const f16x8 pa1 = *(const f16x8*)&Pw[wv][lr][32 + (lg << 3)];
        #pragma unroll
        for (int n = 0; n < 4; ++n) {
            const f16x8 bv0 = *(const f16x8*)&Vt[(n << 4) + lr][lg << 3];
            const f16x8 bv1 = *(const f16x8*)&Vt[(n << 4) + lr][32 + (lg << 3)];
            acc[n] = __builtin_amdgcn_mfma_f32_16x16x32_f16(pa0, bv0, acc[n], 0, 0, 0);
            acc[n] = __builtin_amdgcn_mfma_f32_16x16x32_f16(pa1, bv1, acc[n], 0, 0, 0);
        }
        __syncthreads();
    }

    // epilogue: full row-sum reduce, divide, store fp32
    #pragma unroll
    for (int i = 0; i < 4; ++i) {
        l_i[i] += __shfl_xor(l_i[i], 1);
        l_i[i] += __shfl_xor(l_i[i], 2);
        l_i[i] += __shfl_xor(l_i[i], 4);
        l_i[i] += __shfl_xor(l_i[i], 8);
    }
    #pragma unroll
    for (int n = 0; n < 4; ++n)
        #pragma unroll
        for (int i = 0; i < 4; ++i) {
            const size_t row = (size_t)b * SS + qb + (wv << 4) + (lg << 2) + i;
            O[row * DD + h * DEPTH + (n << 4) + lr] = acc[n][i] / l_i[i];
        }
}

// ---------------------------------------------------------------------------
extern "C" void kernel_launch(void* const* d_in, const int* in_sizes, int n_in,
                              void* d_out, int out_size, void* d_ws, size_t ws_size,
                              hipStream_t stream) {
    const float* v     = (const float*)d_in[0];
    const float* k     = (const float*)d_in[1];
    const float* q     = (const float*)d_in[2];
    const int*   mask  = (const int*)  d_in[3];
    const float* wq_w  = (const float*)d_in[4];
    const float* wq_b  = (const float*)d_in[5];
    const float* wk_w  = (const float*)d_in[6];
    const float* wk_b  = (const float*)d_in[7];
    const float* wv_w  = (const float*)d_in[8];
    const float* wv_b  = (const float*)d_in[9];
    const float* dwq   = (const float*)d_in[10];
    const float* pwq   = (const float*)d_in[11];
    const float* bq    = (const float*)d_in[12];
    const float* dwk   = (const float*)d_in[13];
    const float* pwk   = (const float*)d_in[14];
    const float* bk    = (const float*)d_in[15];
    const float* dwv   = (const float*)d_in[16];
    const float* pwv   = (const float*)d_in[17];
    const float* bv    = (const float*)d_in[18];
    const float* wo_w  = (const float*)d_in[19];
    const float* wo_b  = (const float*)d_in[20];
    float* out = (float*)d_out;

    const size_t NE = (size_t)MTOT * DD;      // 4M elems
    float* s0 = (float*)d_ws;                 // fp32 tmp (proj out)
    float* s3 = s0 + NE;                      // fp32 tmp (dwconv out)
    float* s1 = s3 + NE;                      // fp32 attn out
    f16*   qh = (f16*)(s1 + NE);              // f16 Q/K/V (8MB each)
    f16*   kh = qh + NE;
    f16*   vh = kh + NE;

    const dim3 gg(DD / 128, MTOT / 128);      // (8, 32)
    const int nblk = (int)(NE / 256);         // 16384

    // Q chain
    gemm_f16mfma<0><<<gg, 256, 0, stream>>>(q, wq_w, wq_b, s0, nullptr, DD);
    dwconv3<<<nblk, 256, 0, stream>>>(s0, dwq, s3);
    gemm_f16mfma<1><<<gg, 256, 0, stream>>>(s3, pwq, bq, nullptr, qh, DD);
    // K chain
    gemm_f16mfma<0><<<gg, 256, 0, stream>>>(k, wk_w, wk_b, s0, nullptr, DD);
    dwconv3<<<nblk, 256, 0, stream>>>(s0, dwk, s3);
    gemm_f16mfma<1><<<gg, 256, 0, stream>>>(s3, pwk, bk, nullptr, kh, DD);
    // V chain
    gemm_f16mfma<0><<<gg, 256, 0, stream>>>(v, wv_w, wv_b, s0, nullptr, DD);
    dwconv3<<<nblk, 256, 0, stream>>>(s0, dwv, s3);
    gemm_f16mfma<1><<<gg, 256, 0, stream>>>(s3, pwv, bv, nullptr, vh, DD);

    // Flash attention
    attn_f16<<<dim3(1024), 256, 0, stream>>>(qh, kh, vh, mask, s1);

    // Output dense
    gemm_f16mfma<0><<<gg, 256, 0, stream>>>(s1, wo_w, wo_b, out, nullptr, DD);
}

// Round 3
// 253.017 us; speedup vs baseline: 8.3045x; 1.6182x over previous
//
#include <hip/hip_runtime.h>
#include <hip/hip_fp16.h>
#include <math.h>

#define BB 2
#define SS 2048
#define DD 1024
#define HH 16
#define MTOT (BB*SS)   // 4096

typedef _Float16 f16;
typedef _Float16 f16x4 __attribute__((ext_vector_type(4)));
typedef _Float16 f16x8 __attribute__((ext_vector_type(8)));
typedef float    f32x4 __attribute__((ext_vector_type(4)));

__device__ __forceinline__ float silu_f(float x) {
    return x / (1.0f + __expf(-x));
}

// async global->LDS, 16B per lane. lds base must be wave-uniform; HW writes
// lane l at lds + l*16. Global src is per-lane (carries the swizzle).
__device__ __forceinline__ void gload16(void* lds, const void* g) {
    __builtin_amdgcn_global_load_lds(
        (const __attribute__((address_space(1))) unsigned*)g,
        (__attribute__((address_space(3))) unsigned*)lds, 16, 0, 0);
}

// ---------------------------------------------------------------------------
// fp32 -> f16 elementwise convert (q,k,v), 8 elems/thread. grid (2048, 3).
// ---------------------------------------------------------------------------
__global__ __launch_bounds__(256) void cvt3(
    const float* __restrict__ a0, const float* __restrict__ a1,
    const float* __restrict__ a2, f16* __restrict__ o0,
    f16* __restrict__ o1, f16* __restrict__ o2)
{
    const int z = blockIdx.y;
    const float* src = z == 0 ? a0 : z == 1 ? a1 : a2;
    f16* dst = z == 0 ? o0 : z == 1 ? o1 : o2;
    const size_t i8 = ((size_t)blockIdx.x * 256 + threadIdx.x) * 8;
    const float4 a = *(const float4*)(src + i8);
    const float4 b = *(const float4*)(src + i8 + 4);
    f16x8 h = {(f16)a.x,(f16)a.y,(f16)a.z,(f16)a.w,(f16)b.x,(f16)b.y,(f16)b.z,(f16)b.w};
    *(f16x8*)(dst + i8) = h;
}

// ---------------------------------------------------------------------------
// W fp32 [K=1024][N=1024] -> Wt f16 [N][K]. 64x64 tiles, grid (16,16,7).
// ---------------------------------------------------------------------------
__global__ __launch_bounds__(256) void wtrans(
    const float* w0, const float* w1, const float* w2, const float* w3,
    const float* w4, const float* w5, const float* w6, f16* __restrict__ wt)
{
    __shared__ float ts[64][65];
    const float* src;
    switch (blockIdx.z) {
        case 0: src = w0; break; case 1: src = w1; break;
        case 2: src = w2; break; case 3: src = w3; break;
        case 4: src = w4; break; case 5: src = w5; break;
        default: src = w6; break;
    }
    f16* dst = wt + ((size_t)blockIdx.z << 20);
    const int bk = blockIdx.y << 6, bn = blockIdx.x << 6;
    const int t = threadIdx.x;
    #pragma unroll
    for (int i = 0; i < 4; ++i) {
        const int fid = t + (i << 8);
        const int r = fid >> 4, c4 = (fid & 15) << 2;
        const float4 v4 = *(const float4*)(src + (size_t)(bk + r) * 1024 + bn + c4);
        ts[r][c4 + 0] = v4.x; ts[r][c4 + 1] = v4.y;
        ts[r][c4 + 2] = v4.z; ts[r][c4 + 3] = v4.w;
    }
    __syncthreads();
    #pragma unroll
    for (int i = 0; i < 4; ++i) {
        const int fid = t + (i << 8);
        const int nr = fid >> 4, k4 = (fid & 15) << 2;
        f16x4 h = { (f16)ts[k4 + 0][nr], (f16)ts[k4 + 1][nr],
                    (f16)ts[k4 + 2][nr], (f16)ts[k4 + 3][nr] };
        *(f16x4*)(dst + (size_t)(bn + nr) * 1024 + bk + k4) = h;
    }
}

// ---------------------------------------------------------------------------
// Depthwise conv K=3 SAME, f16 in/out, fp32 math, 8 ch/thread. grid (2048,3).
// ---------------------------------------------------------------------------
__global__ __launch_bounds__(256) void dwconv3g(
    const f16* __restrict__ p0, const f16* __restrict__ p1, const f16* __restrict__ p2,
    const float* __restrict__ w0, const float* __restrict__ w1, const float* __restrict__ w2,
    f16* __restrict__ o0, f16* __restrict__ o1, f16* __restrict__ o2)
{
    const int z = blockIdx.y;
    const f16* x = z == 0 ? p0 : z == 1 ? p1 : p2;
    const float* dw = z == 0 ? w0 : z == 1 ? w1 : w2;
    f16* y = z == 0 ? o0 : z == 1 ? o1 : o2;
    const size_t i8 = ((size_t)blockIdx.x * 256 + threadIdx.x) * 8;
    const int c = (int)(i8 % DD);
    const int s = (int)((i8 / DD) % SS);
    const f16x8 xc = *(const f16x8*)(x + i8);
    float acc[8];
    #pragma unroll
    for (int j = 0; j < 8; ++j) acc[j] = (float)xc[j] * dw[DD + c + j];
    if (s > 0) {
        const f16x8 xm = *(const f16x8*)(x + i8 - DD);
        #pragma unroll
        for (int j = 0; j < 8; ++j) acc[j] = fmaf((float)xm[j], dw[c + j], acc[j]);
    }
    if (s < SS - 1) {
        const f16x8 xp = *(const f16x8*)(x + i8 + DD);
        #pragma unroll
        for (int j = 0; j < 8; ++j) acc[j] = fmaf((float)xp[j], dw[2 * DD + c + j], acc[j]);
    }
    f16x8 o;
    #pragma unroll
    for (int j = 0; j < 8; ++j) o[j] = (f16)acc[j];
    *(f16x8*)(y + i8) = o;
}

// ---------------------------------------------------------------------------
// C = silu(A[4096,1024] @ Wt^T + bias). A f16 [M][K]; Wt f16 [N][K].
// 128x128 tile, BK=64, 4 waves (2x2, 64x64 each), global_load_lds staging,
// both-sides XOR swizzle (16B chunk ^= row&7). grid (8, 32, nbatch).
// ---------------------------------------------------------------------------
struct GArg { const f16* A; const f16* W; const float* b; void* C; };

template<int OUTF32>
__global__ __launch_bounds__(256) void gemm_f16(GArg g0, GArg g1, GArg g2)
{
    __shared__ f16 As[128 * 64];   // 16KB, linear [row][chunk], phys chunk = logical ^ (row&7)
    __shared__ f16 Bs[128 * 64];

    const GArg ga = blockIdx.z == 0 ? g0 : blockIdx.z == 1 ? g1 : g2;
    const int t = threadIdx.x, l = t & 63, wv = t >> 6;
    const int lr = l & 15, lg = l >> 4;
    const int wr = wv >> 1, wc = wv & 1;

    // bijective XCD swizzle within z-slice (256 blocks, 8 XCDs, 32 each)
    const int bid = blockIdx.y * 8 + blockIdx.x;
    const int sw = (bid & 7) * 32 + (bid >> 3);
    const int brow = (sw >> 3) << 7, bcol = (sw & 7) << 7;

    // staging lane constants: instr covers 8 rows x 128B; lane l -> row l>>3,
    // phys chunk l&7, so it must fetch logical chunk (l&7)^(l>>3).
    const int srow = l >> 3;
    const int schk = (l & 7) ^ (l >> 3);
    const f16* Abase = ga.A + (size_t)(brow + wv * 32 + srow) * 1024 + schk * 8;
    const f16* Bbase = ga.W + (size_t)(bcol + wv * 32 + srow) * 1024 + schk * 8;

    f32x4 acc[4][4];
    #pragma unroll
    for (int m = 0; m < 4; ++m)
        #pragma unroll
        for (int n = 0; n < 4; ++n) acc[m][n] = (f32x4){0.f, 0.f, 0.f, 0.f};

    for (int kt = 0; kt < 16; ++kt) {
        const int k0 = kt << 6;
        #pragma unroll
        for (int j = 0; j < 4; ++j) {
            gload16(As + (wv * 4 + j) * 512, Abase + (size_t)j * 8 * 1024 + k0);
            gload16(Bs + (wv * 4 + j) * 512, Bbase + (size_t)j * 8 * 1024 + k0);
        }
        __syncthreads();   // vmcnt(0) drain + barrier

        #pragma unroll
        for (int kk = 0; kk < 2; ++kk) {
            f16x8 af[4], bf[4];
            #pragma unroll
            for (int m = 0; m < 4; ++m) {
                const int row = (wr << 6) + (m << 4) + lr;
                const int off = row * 128 + ((((kk << 6) | (lg << 4))) ^ ((lr & 7) << 4));
                af[m] = *(const f16x8*)((const char*)As + off);
            }
            #pragma unroll
            for (int n = 0; n < 4; ++n) {
                const int row = (wc << 6) + (n << 4) + lr;
                const int off = row * 128 + ((((kk << 6) | (lg << 4))) ^ ((lr & 7) << 4));
                bf[n] = *(const f16x8*)((const char*)Bs + off);
            }
            #pragma unroll
            for (int m = 0; m < 4; ++m)
                #pragma unroll
                for (int n = 0; n < 4; ++n)
                    acc[m][n] = __builtin_amdgcn_mfma_f32_16x16x32_f16(af[m], bf[n], acc[m][n], 0, 0, 0);
        }
        __syncthreads();   // protect LDS overwrite by next stage
    }

    float bv[4];
    #pragma unroll
    for (int n = 0; n < 4; ++n) bv[n] = ga.b[bcol + (wc << 6) + (n << 4) + lr];
    #pragma unroll
    for (int m = 0; m < 4; ++m)
        #pragma unroll
        for (int n = 0; n < 4; ++n)
            #pragma unroll
            for (int i = 0; i < 4; ++i) {
                const int row = brow + (wr << 6) + (m << 4) + (lg << 2) + i;
                const int col = bcol + (wc << 6) + (n << 4) + lr;
                const float o = silu_f(acc[m][n][i] + bv[n]);
                if (OUTF32) ((float*)ga.C)[(size_t)row * 1024 + col] = o;
                else        ((f16*)ga.C)[(size_t)row * 1024 + col] = (f16)o;
            }
}

// ---------------------------------------------------------------------------
// Flash attention, f16 MFMA, fp32 softmax. 64 q-rows/block (4 waves x 16),
// 64-key tiles. K staged via global_load_lds; Ks/Vt/Pw XOR-swizzled [64][64].
// O written f16. grid 1024 blocks, 256 thr.
// ---------------------------------------------------------------------------
__global__ __launch_bounds__(256) void attn_f16(
    const f16* __restrict__ Q, const f16* __restrict__ K,
    const f16* __restrict__ V, const int* __restrict__ mask,
    f16* __restrict__ O)
{
    __shared__ f16 Ks[64 * 64];        // [key][d], swizzled
    __shared__ f16 Vt[64 * 64];        // [d][key], swizzled
    __shared__ f16 Pw[4 * 16 * 64];    // per-wave P [qrow][key], swizzled
    __shared__ int mk[64];

    const int t = threadIdx.x;
    const int l = t & 63, wv = t >> 6;
    const int lr = l & 15, lg = l >> 4;

    const int bid = blockIdx.x;
    const int sw = (bid & 7) * 128 + (bid >> 3);
    const int qb = (sw & 31) << 6;
    const int h  = (sw >> 5) & 15;
    const int b  = sw >> 9;

    const int srow = l >> 3;
    const int schk = (l & 7) ^ (l >> 3);

    const int bkv = (t & 15) << 2;   // key base for V transpose
    const int bnv = (t >> 4) << 2;   // d base

    const size_t qrow = (size_t)b * SS + qb + (wv << 4) + lr;
    const f16x8 aq0 = *(const f16x8*)(Q + qrow * DD + h * 64 + (lg << 3));
    const f16x8 aq1 = *(const f16x8*)(Q + qrow * DD + h * 64 + 32 + (lg << 3));

    float m_i[4], l_i[4];
    f32x4 acc[4];
    #pragma unroll
    for (int i = 0; i < 4; ++i) { m_i[i] = -1e30f; l_i[i] = 0.f; }
    #pragma unroll
    for (int n = 0; n < 4; ++n) acc[n] = (f32x4){0.f, 0.f, 0.f, 0.f};

    const int rdswz = (lr & 7) << 4;   // read-side XOR for frag rows

    for (int kt = 0; kt < SS; kt += 64) {
        // ---- stage K tile via global_load_lds (pre-swizzled source) ----
        #pragma unroll
        for (int j = 0; j < 2; ++j) {
            const int instr = wv * 2 + j;           // 8 rows each
            gload16(Ks + instr * 512,
                    K + ((size_t)b * SS + kt + instr * 8 + srow) * DD + h * 64 + schk * 8);
        }
        // ---- stage V transposed (reg path, swizzled writes) ----
        {
            f16x4 vl[4];
            #pragma unroll
            for (int r = 0; r < 4; ++r)
                vl[r] = *(const f16x4*)(V + ((size_t)b * SS + kt + bkv + r) * DD + h * 64 + bnv);
            #pragma unroll
            for (int j = 0; j < 4; ++j) {
                f16x4 h4 = { vl[0][j], vl[1][j], vl[2][j], vl[3][j] };
                const int row = bnv + j;
                const int off = row * 128 + ((bkv * 2) ^ ((row & 7) << 4));
                *(f16x4*)((char*)Vt + off) = h4;
            }
        }
        if (t < 64) mk[t] = mask[b * SS + kt + t];
        __syncthreads();

        // ---- S = Q K^T ----
        f32x4 s[4];
        #pragma unroll
        for (int n = 0; n < 4; ++n) {
            const int row = (n << 4) + lr;
            const f16x8 bk0 = *(const f16x8*)((const char*)Ks + row * 128 + (((lg << 4)) ^ rdswz));
            const f16x8 bk1 = *(const f16x8*)((const char*)Ks + row * 128 + (((64) | (lg << 4)) ^ rdswz));
            f32x4 z = (f32x4){0.f, 0.f, 0.f, 0.f};
            z = __builtin_amdgcn_mfma_f32_16x16x32_f16(aq0, bk0, z, 0, 0, 0);
            z = __builtin_amdgcn_mfma_f32_16x16x32_f16(aq1, bk1, z, 0, 0, 0);
            const int msk = mk[row];
            #pragma unroll
            for (int i = 0; i < 4; ++i)
                s[n][i] = msk ? -1e30f : z[i] * 0.125f;
        }

        // ---- online softmax (row owned by 16-lane group) ----
        float pm[4];
        #pragma unroll
        for (int i = 0; i < 4; ++i)
            pm[i] = fmaxf(fmaxf(s[0][i], s[1][i]), fmaxf(s[2][i], s[3][i]));
        #pragma unroll
        for (int i = 0; i < 4; ++i) {
            pm[i] = fmaxf(pm[i], __shfl_xor(pm[i], 1));
            pm[i] = fmaxf(pm[i], __shfl_xor(pm[i], 2));
            pm[i] = fmaxf(pm[i], __shfl_xor(pm[i], 4));
            pm[i] = fmaxf(pm[i], __shfl_xor(pm[i], 8));
        }
        float sc[4];
        #pragma unroll
        for (int i = 0; i < 4; ++i) {
            const float mn = fmaxf(m_i[i], pm[i]);
            sc[i] = __expf(m_i[i] - mn);
            m_i[i] = mn;
            l_i[i] *= sc[i];
        }
        #pragma unroll
        for (int n = 0; n < 4; ++n)
            #pragma unroll
            for (int i = 0; i < 4; ++i)
                acc[n][i] *= sc[i];

        // ---- P = exp(s-m) -> Pw (swizzled), accumulate row sums ----
        #pragma unroll
        for (int n = 0; n < 4; ++n)
            #pragma unroll
            for (int i = 0; i < 4; ++i) {
                const float p = __expf(s[n][i] - m_i[i]);
                l_i[i] += p;
                const int row = (lg << 2) + i;
                const int off = (wv << 11) + row * 128 + ((((n << 4) + lr) * 2) ^ ((row & 7) << 4));
                *(f16*)((char*)Pw + off) = (f16)p;
            }

        // ---- O += P V ----
        const int poff = (wv << 11) + lr * 128;
        const f16x8 pa0 = *(const f16x8*)((const char*)Pw + poff + (((lg << 4)) ^ rdswz));
        const f16x8 pa1 = *(const f16x8*)((const char*)Pw + poff + (((64) | (lg << 4)) ^ rdswz));
        #pragma unroll
        for (int n = 0; n < 4; ++n) {
            const int row = (n << 4) + lr;
            const f16x8 bv0 = *(const f16x8*)((const char*)Vt + row * 128 + (((lg << 4)) ^ rdswz));
            const f16x8 bv1 = *(const f16x8*)((const char*)Vt + row * 128 + (((64) | (lg << 4)) ^ rdswz));
            acc[n] = __builtin_amdgcn_mfma_f32_16x16x32_f16(pa0, bv0, acc[n], 0, 0, 0);
            acc[n] = __builtin_amdgcn_mfma_f32_16x16x32_f16(pa1, bv1, acc[n], 0, 0, 0);
        }
        __syncthreads();
    }

    #pragma unroll
    for (int i = 0; i < 4; ++i) {
        l_i[i] += __shfl_xor(l_i[i], 1);
        l_i[i] += __shfl_xor(l_i[i], 2);
        l_i[i] += __shfl_xor(l_i[i], 4);
        l_i[i] += __shfl_xor(l_i[i], 8);
    }
    #pragma unroll
    for (int n = 0; n < 4; ++n)
        #pragma unroll
        for (int i = 0; i < 4; ++i) {
            const size_t row = (size_t)b * SS + qb + (wv << 4) + (lg << 2) + i;
            O[row * DD + h * 64 + (n << 4) + lr] = (f16)(acc[n][i] / l_i[i]);
        }
}

// ---------------------------------------------------------------------------
extern "C" void kernel_launch(void* const* d_in, const int* in_sizes, int n_in,
                              void* d_out, int out_size, void* d_ws, size_t ws_size,
                              hipStream_t stream) {
    const float* v    = (const float*)d_in[0];
    const float* k    = (const float*)d_in[1];
    const float* q    = (const float*)d_in[2];
    const int*   mask = (const int*)  d_in[3];
    const float* wq_w = (const float*)d_in[4];
    const float* wq_b = (const float*)d_in[5];
    const float* wk_w = (const float*)d_in[6];
    const float* wk_b = (const float*)d_in[7];
    const float* wv_w = (const float*)d_in[8];
    const float* wv_b = (const float*)d_in[9];
    const float* dwq  = (const float*)d_in[10];
    const float* pwq  = (const float*)d_in[11];
    const float* bq   = (const float*)d_in[12];
    const float* dwk  = (const float*)d_in[13];
    const float* pwk  = (const float*)d_in[14];
    const float* bk   = (const float*)d_in[15];
    const float* dwv  = (const float*)d_in[16];
    const float* pwv  = (const float*)d_in[17];
    const float* bv   = (const float*)d_in[18];
    const float* wo_w = (const float*)d_in[19];
    const float* wo_b = (const float*)d_in[20];
    float* out = (float*)d_out;

    const size_t NE = (size_t)MTOT * DD;        // 4M elems
    f16* wt = (f16*)d_ws;                       // 7 x 1M f16 (14MB)
    f16* x0 = wt + 7 * (size_t)(1 << 20);       // 3 x 4M f16 (24MB)
    f16* x1 = x0 + NE;
    f16* x2 = x1 + NE;
    f16* p0 = x2 + NE;                          // 3 x 4M f16 (24MB)
    f16* p1 = p0 + NE;
    f16* p2 = p1 + NE;
    f16* ao = p2 + NE;                          // 4M f16 (8MB)

    f16* wtq = wt,            *wtk = wt + (1u<<20), *wtv = wt + 2*(1u<<20);
    f16* wpq = wt + 3*(1u<<20), *wpk = wt + 4*(1u<<20), *wpv = wt + 5*(1u<<20);
    f16* wto = wt + 6*(1u<<20);

    // 1. convert q,k,v to f16  (chain order: 0=q, 1=k, 2=v)
    cvt3<<<dim3(2048, 3), 256, 0, stream>>>(q, k, v, x0, x1, x2);
    // 2. transpose+convert 7 weights
    wtrans<<<dim3(16, 16, 7), 256, 0, stream>>>(wq_w, wk_w, wv_w, pwq, pwk, pwv, wo_w, wt);
    // 3. projection GEMMs (batched)
    gemm_f16<0><<<dim3(8, 32, 3), 256, 0, stream>>>(
        GArg{x0, wtq, wq_b, p0}, GArg{x1, wtk, wk_b, p1}, GArg{x2, wtv, wv_b, p2});
    // 4. depthwise convs (batched), write back into x*
    dwconv3g<<<dim3(2048, 3), 256, 0, stream>>>(p0, p1, p2, dwq, dwk, dwv, x0, x1, x2);
    // 5. pointwise GEMMs (batched) -> qh/kh/vh in p*
    gemm_f16<0><<<dim3(8, 32, 3), 256, 0, stream>>>(
        GArg{x0, wpq, bq, p0}, GArg{x1, wpk, bk, p1}, GArg{x2, wpv, bv, p2});
    // 6. flash attention -> ao (f16)
    attn_f16<<<dim3(1024), 256, 0, stream>>>(p0, p1, p2, mask, ao);
    // 7. output dense -> fp32 d_out
    gemm_f16<1><<<dim3(8, 32, 1), 256, 0, stream>>>(
        GArg{ao, wto, wo_b, out}, GArg{ao, wto, wo_b, out}, GArg{ao, wto, wo_b, out});
}